// Round 2
// baseline (58.207 us; speedup 1.0000x reference)
//
#include <hip/hip_runtime.h>

// Problem constants
#define BB 8
#define SS 2048
#define FF 256
#define HH 8
#define DD 64
#define PROJ 512
#define NCHUNK 32
#define CHUNK (SS / NCHUNK) // 64

// ---------------------------------------------------------------------------
// K1: per (b,h): q_h = x[b,S-1,:] @ Wq[:, h*64:(h+1)*64]
//     r[b,h,f]  = (1/8) * sum_d Wk[f, h*64+d] * q_h[d]
// grid = B*H, block = 256
// ---------------------------------------------------------------------------
__global__ void k_qr(const float* __restrict__ x, const float* __restrict__ Wq,
                     const float* __restrict__ Wk, float* __restrict__ r) {
    const int b = blockIdx.x / HH;
    const int h = blockIdx.x % HH;
    __shared__ float xrow[FF];
    __shared__ float qh[DD];
    const int t = threadIdx.x;

    xrow[t] = x[((size_t)b * SS + (SS - 1)) * FF + t];
    __syncthreads();

    if (t < DD) {
        float acc = 0.f;
        for (int f = 0; f < FF; ++f)
            acc += xrow[f] * Wq[f * PROJ + h * DD + t];
        qh[t] = acc;
    }
    __syncthreads();

    // r[f=t]
    const float4* wk4 = reinterpret_cast<const float4*>(Wk + (size_t)t * PROJ + h * DD);
    float acc = 0.f;
#pragma unroll
    for (int d4 = 0; d4 < DD / 4; ++d4) {
        float4 w = wk4[d4];
        acc += w.x * qh[d4 * 4 + 0] + w.y * qh[d4 * 4 + 1] +
               w.z * qh[d4 * 4 + 2] + w.w * qh[d4 * 4 + 3];
    }
    r[(size_t)blockIdx.x * FF + t] = acc * 0.125f; // fold 1/sqrt(64)
}

// ---------------------------------------------------------------------------
// K2: sc[b,h,s] = x[b,s,:] . r[b,h,:]   (scale already folded into r)
// grid = B*NCHUNK, block = 512 ; each thread: one (s_local, h)
// ---------------------------------------------------------------------------
__global__ void k_scores(const float* __restrict__ x, const float* __restrict__ r,
                         float* __restrict__ sc) {
    const int b = blockIdx.x / NCHUNK;
    const int c = blockIdx.x % NCHUNK;
    __shared__ float rl[HH][FF + 4]; // +4 pad breaks 8-way bank conflict
    const int t = threadIdx.x;

    for (int i = t; i < HH * FF; i += 512)
        rl[i >> 8][i & 255] = r[(size_t)b * HH * FF + i];
    __syncthreads();

    const int sl = t >> 3; // 0..63
    const int h  = t & 7;
    const float4* xp =
        reinterpret_cast<const float4*>(x + ((size_t)b * SS + c * CHUNK + sl) * FF);
    const float* rp = rl[h];
    float acc = 0.f;
#pragma unroll 8
    for (int f4 = 0; f4 < FF / 4; ++f4) {
        float4 xv = xp[f4];
        acc += xv.x * rp[f4 * 4 + 0] + xv.y * rp[f4 * 4 + 1] +
               xv.z * rp[f4 * 4 + 2] + xv.w * rp[f4 * 4 + 3];
    }
    sc[((size_t)(b * HH + h)) * SS + c * CHUNK + sl] = acc;
}

// ---------------------------------------------------------------------------
// K3: softmax over S per (b,h): write back unnormalized exp(s - max), store sum
// grid = B*H, block = 256 (4 waves)
// ---------------------------------------------------------------------------
__global__ void k_softmax(float* __restrict__ sc, float* __restrict__ denom) {
    const int bh = blockIdx.x;
    float* row = sc + (size_t)bh * SS;
    const int t = threadIdx.x;
    const int wv = t >> 6, ln = t & 63;

    float v[8];
    float m = -1e30f;
#pragma unroll
    for (int i = 0; i < 8; ++i) {
        v[i] = row[i * 256 + t];
        m = fmaxf(m, v[i]);
    }
    __shared__ float redm[4], reds[4];
#pragma unroll
    for (int off = 32; off; off >>= 1) m = fmaxf(m, __shfl_xor(m, off));
    if (ln == 0) redm[wv] = m;
    __syncthreads();
    m = fmaxf(fmaxf(redm[0], redm[1]), fmaxf(redm[2], redm[3]));

    float ssum = 0.f;
#pragma unroll
    for (int i = 0; i < 8; ++i) {
        v[i] = expf(v[i] - m);
        ssum += v[i];
    }
#pragma unroll
    for (int off = 32; off; off >>= 1) ssum += __shfl_xor(ssum, off);
    if (ln == 0) reds[wv] = ssum;
    __syncthreads();
    ssum = reds[0] + reds[1] + reds[2] + reds[3];

#pragma unroll
    for (int i = 0; i < 8; ++i) row[i * 256 + t] = v[i];
    if (t == 0) denom[bh] = ssum;
}

// ---------------------------------------------------------------------------
// K4: ypart[b,c,h,f] = sum_{s in chunk} wt[b,h,s] * x[b,s,f]
// grid = B*NCHUNK, block = 256 (thread = f)
// ---------------------------------------------------------------------------
__global__ void k_ypart(const float* __restrict__ x, const float* __restrict__ wt,
                        float* __restrict__ ypart) {
    const int b = blockIdx.x / NCHUNK;
    const int c = blockIdx.x % NCHUNK;
    __shared__ float wl[HH][CHUNK];
    const int t = threadIdx.x;

    for (int i = t; i < HH * CHUNK; i += 256) {
        const int h = i / CHUNK, s = i % CHUNK;
        wl[h][s] = wt[((size_t)(b * HH + h)) * SS + c * CHUNK + s];
    }
    __syncthreads();

    float acc[HH] = {0, 0, 0, 0, 0, 0, 0, 0};
    const float* xp = x + ((size_t)b * SS + c * CHUNK) * FF + t;
    for (int s = 0; s < CHUNK; ++s) {
        const float xv = xp[(size_t)s * FF];
#pragma unroll
        for (int h = 0; h < HH; ++h) acc[h] += wl[h][s] * xv;
    }
    float* yp = ypart + (size_t)blockIdx.x * HH * FF;
#pragma unroll
    for (int h = 0; h < HH; ++h) yp[h * FF + t] = acc[h];
}

// ---------------------------------------------------------------------------
// K5: per b: y = sum_c ypart ; attn[p] = (y[h,:].Wv[:,p]) / denom[h] ;
//     out[b,f] = bo[f] + sum_p attn[p] * Wo[p,f]
// grid = B, block = 256
// ---------------------------------------------------------------------------
__global__ void k_final(const float* __restrict__ ypart, const float* __restrict__ denom,
                        const float* __restrict__ Wv, const float* __restrict__ Wo,
                        const float* __restrict__ bo, float* __restrict__ out) {
    const int b = blockIdx.x;
    __shared__ float yt[HH][FF];  // 8 KB
    __shared__ float at[PROJ];    // 2 KB
    __shared__ float dinv[HH];
    const int t = threadIdx.x;

    if (t < HH) dinv[t] = 1.f / denom[b * HH + t];
#pragma unroll
    for (int h = 0; h < HH; ++h) {
        float acc = 0.f;
        for (int c = 0; c < NCHUNK; ++c)
            acc += ypart[((size_t)(b * NCHUNK + c)) * HH * FF + h * FF + t];
        yt[h][t] = acc;
    }
    __syncthreads();

#pragma unroll
    for (int rep = 0; rep < 2; ++rep) {
        const int p = rep * 256 + t;
        const int h = p >> 6;
        float acc = 0.f;
        for (int f = 0; f < FF; ++f)
            acc += yt[h][f] * Wv[(size_t)f * PROJ + p];
        at[p] = acc * dinv[h];
    }
    __syncthreads();

    float acc = bo[t];
    for (int p = 0; p < PROJ; ++p)
        acc += at[p] * Wo[(size_t)p * FF + t];
    out[(size_t)b * FF + t] = acc;
}

// ---------------------------------------------------------------------------
extern "C" void kernel_launch(void* const* d_in, const int* in_sizes, int n_in,
                              void* d_out, int out_size, void* d_ws, size_t ws_size,
                              hipStream_t stream) {
    const float* x  = (const float*)d_in[0];
    const float* Wq = (const float*)d_in[1];
    const float* Wk = (const float*)d_in[2];
    const float* Wv = (const float*)d_in[3];
    const float* Wo = (const float*)d_in[4];
    const float* bo = (const float*)d_in[5];
    float* out = (float*)d_out;

    float* ws    = (float*)d_ws;
    float* r     = ws;                    // B*H*F      = 16384
    float* sc    = r + BB * HH * FF;      // B*H*S      = 131072
    float* denom = sc + (size_t)BB * HH * SS; // B*H    = 64
    float* ypart = denom + BB * HH;       // B*NCHUNK*H*F = 524288

    k_qr<<<BB * HH, 256, 0, stream>>>(x, Wq, Wk, r);
    k_scores<<<BB * NCHUNK, 512, 0, stream>>>(x, r, sc);
    k_softmax<<<BB * HH, 256, 0, stream>>>(sc, denom);
    k_ypart<<<BB * NCHUNK, 256, 0, stream>>>(x, sc, ypart);
    k_final<<<BB, 256, 0, stream>>>(ypart, denom, Wv, Wo, bo, out);
}

// Round 4
// 45.678 us; speedup vs baseline: 1.2743x; 1.2743x over previous
//
#include <hip/hip_runtime.h>

// Problem constants
#define BB 8
#define SS 2048
#define FF 256
#define HH 8
#define DD 64
#define PROJ 512
#define NCHUNK 32
#define CHUNK (SS / NCHUNK) // 64
#define PSLICE 8            // p-dim slices for the output GEMV
#define PSL (PROJ / PSLICE) // 64

// ---------------------------------------------------------------------------
// K1: per (b,h): q_h = x[b,S-1,:] @ Wq[:, h*64:(h+1)*64]
//     r[b,h,f]  = (1/8) * sum_d Wk[f, h*64+d] * q_h[d]
// grid = B*H, block = 256
// ---------------------------------------------------------------------------
__global__ void k_qr(const float* __restrict__ x, const float* __restrict__ Wq,
                     const float* __restrict__ Wk, float* __restrict__ r) {
    const int b = blockIdx.x / HH;
    const int h = blockIdx.x % HH;
    __shared__ float xrow[FF];
    __shared__ float qh[DD];
    const int t = threadIdx.x;

    xrow[t] = x[((size_t)b * SS + (SS - 1)) * FF + t];
    __syncthreads();

    if (t < DD) {
        float acc = 0.f;
        for (int f = 0; f < FF; ++f)
            acc += xrow[f] * Wq[f * PROJ + h * DD + t];
        qh[t] = acc;
    }
    __syncthreads();

    // r[f=t]
    const float4* wk4 = reinterpret_cast<const float4*>(Wk + (size_t)t * PROJ + h * DD);
    float acc = 0.f;
#pragma unroll
    for (int d4 = 0; d4 < DD / 4; ++d4) {
        float4 w = wk4[d4];
        acc += w.x * qh[d4 * 4 + 0] + w.y * qh[d4 * 4 + 1] +
               w.z * qh[d4 * 4 + 2] + w.w * qh[d4 * 4 + 3];
    }
    r[(size_t)blockIdx.x * FF + t] = acc * 0.125f; // fold 1/sqrt(64)
}

// ---------------------------------------------------------------------------
// K2: sc[b,h,s] = x[b,s,:] . r[b,h,:]   (scale already folded into r)
// grid = B*NCHUNK, block = 512 ; each thread: one (s_local, h)
// ---------------------------------------------------------------------------
__global__ void k_scores(const float* __restrict__ x, const float* __restrict__ r,
                         float* __restrict__ sc) {
    const int b = blockIdx.x / NCHUNK;
    const int c = blockIdx.x % NCHUNK;
    __shared__ float rl[HH][FF + 4]; // +4 pad breaks 8-way bank conflict
    const int t = threadIdx.x;

    for (int i = t; i < HH * FF; i += 512)
        rl[i >> 8][i & 255] = r[(size_t)b * HH * FF + i];
    __syncthreads();

    const int sl = t >> 3; // 0..63
    const int h  = t & 7;
    const float4* xp =
        reinterpret_cast<const float4*>(x + ((size_t)b * SS + c * CHUNK + sl) * FF);
    const float* rp = rl[h];
    float acc = 0.f;
#pragma unroll 8
    for (int f4 = 0; f4 < FF / 4; ++f4) {
        float4 xv = xp[f4];
        acc += xv.x * rp[f4 * 4 + 0] + xv.y * rp[f4 * 4 + 1] +
               xv.z * rp[f4 * 4 + 2] + xv.w * rp[f4 * 4 + 3];
    }
    sc[((size_t)(b * HH + h)) * SS + c * CHUNK + sl] = acc;
}

// ---------------------------------------------------------------------------
// K3: softmax over S per (b,h): write back unnormalized exp(s - max), store sum
// grid = B*H, block = 256 (4 waves)
// ---------------------------------------------------------------------------
__global__ void k_softmax(float* __restrict__ sc, float* __restrict__ denom) {
    const int bh = blockIdx.x;
    float* row = sc + (size_t)bh * SS;
    const int t = threadIdx.x;
    const int wv = t >> 6, ln = t & 63;

    float v[8];
    float m = -1e30f;
#pragma unroll
    for (int i = 0; i < 8; ++i) {
        v[i] = row[i * 256 + t];
        m = fmaxf(m, v[i]);
    }
    __shared__ float redm[4], reds[4];
#pragma unroll
    for (int off = 32; off; off >>= 1) m = fmaxf(m, __shfl_xor(m, off));
    if (ln == 0) redm[wv] = m;
    __syncthreads();
    m = fmaxf(fmaxf(redm[0], redm[1]), fmaxf(redm[2], redm[3]));

    float ssum = 0.f;
#pragma unroll
    for (int i = 0; i < 8; ++i) {
        v[i] = expf(v[i] - m);
        ssum += v[i];
    }
#pragma unroll
    for (int off = 32; off; off >>= 1) ssum += __shfl_xor(ssum, off);
    if (ln == 0) reds[wv] = ssum;
    __syncthreads();
    ssum = reds[0] + reds[1] + reds[2] + reds[3];

#pragma unroll
    for (int i = 0; i < 8; ++i) row[i * 256 + t] = v[i];
    if (t == 0) denom[bh] = ssum;
}

// ---------------------------------------------------------------------------
// K4: ypart[b,c,h,f] = sum_{s in chunk} wt[b,h,s] * x[b,s,f]
// grid = B*NCHUNK, block = 256 (thread = f)
// ---------------------------------------------------------------------------
__global__ void k_ypart(const float* __restrict__ x, const float* __restrict__ wt,
                        float* __restrict__ ypart) {
    const int b = blockIdx.x / NCHUNK;
    const int c = blockIdx.x % NCHUNK;
    __shared__ float wl[HH][CHUNK];
    const int t = threadIdx.x;

    for (int i = t; i < HH * CHUNK; i += 256) {
        const int h = i / CHUNK, s = i % CHUNK;
        wl[h][s] = wt[((size_t)(b * HH + h)) * SS + c * CHUNK + s];
    }
    __syncthreads();

    float acc[HH] = {0, 0, 0, 0, 0, 0, 0, 0};
    const float* xp = x + ((size_t)b * SS + c * CHUNK) * FF + t;
    for (int s = 0; s < CHUNK; ++s) {
        const float xv = xp[(size_t)s * FF];
#pragma unroll
        for (int h = 0; h < HH; ++h) acc[h] += wl[h][s] * xv;
    }
    float* yp = ypart + (size_t)blockIdx.x * HH * FF;
#pragma unroll
    for (int h = 0; h < HH; ++h) yp[h * FF + t] = acc[h];
}

// ---------------------------------------------------------------------------
// K5a: per (b,h): y[f] = sum_c ypart[b,c,h,f]  (LDS), then project the head's
//      64 Wv columns: attn_g[b, h*64+d] = (sum_f y[f]*Wv[f, h*64+d]) / denom
// grid = B*H = 64, block = 256 (t = q*64+d : 4 f-quarters x 64 cols)
// ---------------------------------------------------------------------------
__global__ void k_attn(const float* __restrict__ ypart, const float* __restrict__ denom,
                       const float* __restrict__ Wv, float* __restrict__ attn_g) {
    const int b = blockIdx.x / HH;
    const int h = blockIdx.x % HH;
    const int t = threadIdx.x;
    __shared__ float yt[FF];
    __shared__ float atl[4][DD];

    // y-reduce over 32 chunks, thread = f
    {
        float acc = 0.f;
        const float* yp = ypart + ((size_t)b * NCHUNK) * HH * FF + h * FF + t;
#pragma unroll 8
        for (int c = 0; c < NCHUNK; ++c)
            acc += yp[(size_t)c * HH * FF];
        yt[t] = acc;
    }
    __syncthreads();

    // Wv projection: t = q*64 + d; each thread: 64 f-values of column h*64+d
    const int q = t >> 6;   // 0..3
    const int d = t & 63;   // 0..63
    {
        float acc = 0.f;
        const float* wvp = Wv + (size_t)(q * 64) * PROJ + h * DD + d;
#pragma unroll 8
        for (int j = 0; j < 64; ++j)
            acc += yt[q * 64 + j] * wvp[(size_t)j * PROJ];
        atl[q][d] = acc;
    }
    __syncthreads();

    if (t < DD) {
        const float dinv = 1.f / denom[b * HH + h];
        attn_g[(size_t)b * PROJ + h * DD + t] =
            (atl[0][t] + atl[1][t] + atl[2][t] + atl[3][t]) * dinv;
    }
}

// ---------------------------------------------------------------------------
// K5b: per (b, slice): po[b,slice,f] = sum_{j<64} attn_g[b, slice*64+j] * Wo[slice*64+j, f]
// grid = B*PSLICE = 64, block = 256 (t = f)
// ---------------------------------------------------------------------------
__global__ void k_out(const float* __restrict__ attn_g, const float* __restrict__ Wo,
                      float* __restrict__ po) {
    const int b  = blockIdx.x / PSLICE;
    const int sl = blockIdx.x % PSLICE;
    const int t  = threadIdx.x;
    __shared__ float al[PSL];

    if (t < PSL) al[t] = attn_g[(size_t)b * PROJ + sl * PSL + t];
    __syncthreads();

    float acc = 0.f;
    const float* wop = Wo + (size_t)(sl * PSL) * FF + t;
#pragma unroll 8
    for (int j = 0; j < PSL; ++j)
        acc += al[j] * wop[(size_t)j * FF];
    po[(size_t)blockIdx.x * FF + t] = acc;
}

// ---------------------------------------------------------------------------
// K5c: out[b,f] = bo[f] + sum_slice po[b,slice,f]
// grid = B, block = 256
// ---------------------------------------------------------------------------
__global__ void k_red(const float* __restrict__ po, const float* __restrict__ bo,
                      float* __restrict__ out) {
    const int b = blockIdx.x;
    const int t = threadIdx.x;
    float acc = bo[t];
#pragma unroll
    for (int sl = 0; sl < PSLICE; ++sl)
        acc += po[((size_t)b * PSLICE + sl) * FF + t];
    out[(size_t)b * FF + t] = acc;
}

// ---------------------------------------------------------------------------
extern "C" void kernel_launch(void* const* d_in, const int* in_sizes, int n_in,
                              void* d_out, int out_size, void* d_ws, size_t ws_size,
                              hipStream_t stream) {
    const float* x  = (const float*)d_in[0];
    const float* Wq = (const float*)d_in[1];
    const float* Wk = (const float*)d_in[2];
    const float* Wv = (const float*)d_in[3];
    const float* Wo = (const float*)d_in[4];
    const float* bo = (const float*)d_in[5];
    float* out = (float*)d_out;

    float* ws     = (float*)d_ws;
    float* r      = ws;                       // B*H*F          = 16384
    float* sc     = r + BB * HH * FF;         // B*H*S          = 131072
    float* denom  = sc + (size_t)BB * HH * SS;// B*H            = 64
    float* ypart  = denom + BB * HH;          // B*NCHUNK*H*F   = 524288
    float* attn_g = ypart + (size_t)BB * NCHUNK * HH * FF; // B*PROJ = 4096
    float* po     = attn_g + BB * PROJ;       // B*PSLICE*F     = 16384

    k_qr<<<BB * HH, 256, 0, stream>>>(x, Wq, Wk, r);
    k_scores<<<BB * NCHUNK, 512, 0, stream>>>(x, r, sc);
    k_softmax<<<BB * HH, 256, 0, stream>>>(sc, denom);
    k_ypart<<<BB * NCHUNK, 256, 0, stream>>>(x, sc, ypart);
    k_attn<<<BB * HH, 256, 0, stream>>>(ypart, denom, Wv, attn_g);
    k_out<<<BB * PSLICE, 256, 0, stream>>>(attn_g, Wo, po);
    k_red<<<BB, 256, 0, stream>>>(po, bo, out);
}

// Round 5
// 34.425 us; speedup vs baseline: 1.6908x; 1.3269x over previous
//
#include <hip/hip_runtime.h>

// Problem constants
#define BB 8
#define SS 2048
#define FF 256
#define HH 8
#define DD 64
#define PROJ 512
#define NCHUNK 32
#define CHUNK (SS / NCHUNK) // 64

// ---------------------------------------------------------------------------
// K1: per (b,h): q_h = x[b,S-1,:] @ Wq[:, h*64:(h+1)*64]
//     r[b,h,f]  = (1/8) * sum_d Wk[f, h*64+d] * q_h[d]
// grid = B*H = 64, block = 256
// ---------------------------------------------------------------------------
__global__ void k_qr(const float* __restrict__ x, const float* __restrict__ Wq,
                     const float* __restrict__ Wk, float* __restrict__ r) {
    const int b = blockIdx.x / HH;
    const int h = blockIdx.x % HH;
    __shared__ float xrow[FF];
    __shared__ float qp[4][DD]; // partial q over 4 f-groups
    __shared__ float qh[DD];
    const int t = threadIdx.x;

    xrow[t] = x[((size_t)b * SS + (SS - 1)) * FF + t];
    __syncthreads();

    // q partials: t = g*64 + d, g in 0..3 covers f in [g*64, g*64+64)
    {
        const int g = t >> 6, d = t & 63;
        float acc = 0.f;
        const float* wqp = Wq + (size_t)(g * 64) * PROJ + h * DD + d;
#pragma unroll 8
        for (int j = 0; j < 64; ++j)
            acc += xrow[g * 64 + j] * wqp[(size_t)j * PROJ];
        qp[g][d] = acc;
    }
    __syncthreads();
    if (t < DD) qh[t] = qp[0][t] + qp[1][t] + qp[2][t] + qp[3][t];
    __syncthreads();

    // r[f=t] = (1/8) * sum_d Wk[f, h*64+d] * qh[d]
    const float4* wk4 = reinterpret_cast<const float4*>(Wk + (size_t)t * PROJ + h * DD);
    float acc = 0.f;
#pragma unroll
    for (int d4 = 0; d4 < DD / 4; ++d4) {
        float4 w = wk4[d4];
        acc += w.x * qh[d4 * 4 + 0] + w.y * qh[d4 * 4 + 1] +
               w.z * qh[d4 * 4 + 2] + w.w * qh[d4 * 4 + 3];
    }
    r[(size_t)blockIdx.x * FF + t] = acc * 0.125f; // fold 1/sqrt(64)
}

// ---------------------------------------------------------------------------
// K2 (flash chunk): per (b, chunk c of 64 rows):
//   sc[h][sl] = x[b, c*64+sl, :] . r[b,h,:]          (one x read)
//   m[h] = max_sl sc ; e = exp(sc - m) ; l[h] = sum e
//   ycp[b,c,h,f] = sum_sl e[h][sl] * x[b, c*64+sl, f]
// grid = B*NCHUNK = 256, block = 512 (8 waves)
// ---------------------------------------------------------------------------
__global__ void k_fa(const float* __restrict__ x, const float* __restrict__ r,
                     float* __restrict__ ycp, float* __restrict__ ml) {
    const int b = blockIdx.x / NCHUNK;
    const int c = blockIdx.x % NCHUNK;
    const int t = threadIdx.x;
    __shared__ float rl[HH][FF + 4];     // 8.3 KB
    __shared__ float es[HH][CHUNK + 4];  // 2.2 KB scores -> exp weights
    __shared__ float yp[2][HH][FF];      // 16 KB

    // load r for all heads
    for (int i = t; i < HH * FF; i += 512)
        rl[i >> 8][i & 255] = r[(size_t)b * HH * FF + i];
    __syncthreads();

    // phase 1: scores. t = sl*8 + h
    {
        const int sl = t >> 3, h = t & 7;
        const float4* xp =
            reinterpret_cast<const float4*>(x + ((size_t)b * SS + c * CHUNK + sl) * FF);
        const float* rp = rl[h];
        float acc = 0.f;
#pragma unroll 8
        for (int f4 = 0; f4 < FF / 4; ++f4) {
            float4 xv = xp[f4];
            acc += xv.x * rp[f4 * 4 + 0] + xv.y * rp[f4 * 4 + 1] +
                   xv.z * rp[f4 * 4 + 2] + xv.w * rp[f4 * 4 + 3];
        }
        es[h][sl] = acc;
    }
    __syncthreads();

    // phase 2: per-head chunk softmax (unnormalized). wave wv owns head wv.
    {
        const int h = t >> 6, ln = t & 63;
        float v = es[h][ln];
        float m = v;
#pragma unroll
        for (int off = 32; off; off >>= 1) m = fmaxf(m, __shfl_xor(m, off));
        float e = __expf(v - m);
        float l = e;
#pragma unroll
        for (int off = 32; off; off >>= 1) l += __shfl_xor(l, off);
        es[h][ln] = e;
        if (ln == 0) {
            float* mlp = ml + ((size_t)(b * NCHUNK + c)) * 2 * HH;
            mlp[h] = m;
            mlp[HH + h] = l;
        }
    }
    __syncthreads();

    // phase 3: y chunk-partials. t = half*256 + f ; half covers 32 s each
    {
        const int f = t & 255, half = t >> 8;
        float acc[HH] = {0, 0, 0, 0, 0, 0, 0, 0};
        const float* xp = x + ((size_t)b * SS + c * CHUNK + half * 32) * FF + f;
        for (int s = 0; s < 32; ++s) {
            const float xv = xp[(size_t)s * FF];
            const int sl = half * 32 + s;
#pragma unroll
            for (int h = 0; h < HH; ++h) acc[h] += es[h][sl] * xv;
        }
#pragma unroll
        for (int h = 0; h < HH; ++h) yp[half][h][f] = acc[h];
    }
    __syncthreads();

    // phase 4: reduce halves, write chunk y
    for (int i = t; i < HH * FF; i += 512) {
        const int h = i >> 8, f = i & 255;
        ycp[((size_t)(b * NCHUNK + c) * HH + h) * FF + f] = yp[0][h][f] + yp[1][h][f];
    }
}

// ---------------------------------------------------------------------------
// K3: per (b,h): M = max_c m_c ; alpha_c = exp(m_c - M) ; L = sum alpha_c*l_c
//     y[f] = sum_c alpha_c * ycp[b,c,h,f]
//     attn_g[b, h*64+d] = (sum_f y[f] * Wv[f, h*64+d]) / L
// grid = B*H = 64, block = 256
// ---------------------------------------------------------------------------
__global__ void k_comb(const float* __restrict__ ycp, const float* __restrict__ ml,
                       const float* __restrict__ Wv, float* __restrict__ attn_g) {
    const int b = blockIdx.x / HH;
    const int h = blockIdx.x % HH;
    const int t = threadIdx.x;
    __shared__ float alpha[NCHUNK];
    __shared__ float Ls;
    __shared__ float yt[FF];
    __shared__ float atl[4][DD];

    if (t < 64) {
        const int ln = t;
        const float* mlp = ml + ((size_t)(b * NCHUNK + (ln & 31))) * 2 * HH;
        float m = (ln < NCHUNK) ? mlp[h] : -1e30f;
        float M = m;
#pragma unroll
        for (int off = 32; off; off >>= 1) M = fmaxf(M, __shfl_xor(M, off));
        float a = (ln < NCHUNK) ? __expf(m - M) : 0.f;
        float lw = (ln < NCHUNK) ? a * mlp[HH + h] : 0.f;
#pragma unroll
        for (int off = 32; off; off >>= 1) lw += __shfl_xor(lw, off);
        if (ln < NCHUNK) alpha[ln] = a;
        if (ln == 0) Ls = lw;
    }
    __syncthreads();

    // y[f]: rescaled chunk combine
    {
        float acc = 0.f;
        const float* yp = ycp + ((size_t)(b * NCHUNK) * HH + h) * FF + t;
#pragma unroll 8
        for (int c = 0; c < NCHUNK; ++c)
            acc += alpha[c] * yp[(size_t)c * HH * FF];
        yt[t] = acc;
    }
    __syncthreads();

    // Wv projection: t = q*64 + d
    {
        const int q = t >> 6, d = t & 63;
        float acc = 0.f;
        const float* wvp = Wv + (size_t)(q * 64) * PROJ + h * DD + d;
#pragma unroll 8
        for (int j = 0; j < 64; ++j)
            acc += yt[q * 64 + j] * wvp[(size_t)j * PROJ];
        atl[q][d] = acc;
    }
    __syncthreads();

    if (t < DD) {
        attn_g[(size_t)b * PROJ + h * DD + t] =
            (atl[0][t] + atl[1][t] + atl[2][t] + atl[3][t]) / Ls;
    }
}

// ---------------------------------------------------------------------------
// K4: per b: out[b,f] = bo[f] + sum_p attn_g[b,p] * Wo[p,f]
// grid = B = 8, block = 1024 (t = sl*256 + f ; 4 p-slices of 128)
// ---------------------------------------------------------------------------
__global__ void k_out2(const float* __restrict__ attn_g, const float* __restrict__ Wo,
                       const float* __restrict__ bo, float* __restrict__ out) {
    const int b = blockIdx.x;
    const int t = threadIdx.x;
    __shared__ float al[PROJ];
    __shared__ float po[4][FF];

    if (t < PROJ) al[t] = attn_g[(size_t)b * PROJ + t];
    __syncthreads();

    {
        const int f = t & 255, sl = t >> 8;
        float acc = 0.f;
        const float* wop = Wo + (size_t)(sl * 128) * FF + f;
        const float* ap = al + sl * 128;
#pragma unroll 8
        for (int j = 0; j < 128; ++j)
            acc += ap[j] * wop[(size_t)j * FF];
        po[sl][f] = acc;
    }
    __syncthreads();

    if (t < FF)
        out[(size_t)b * FF + t] = bo[t] + po[0][t] + po[1][t] + po[2][t] + po[3][t];
}

// ---------------------------------------------------------------------------
extern "C" void kernel_launch(void* const* d_in, const int* in_sizes, int n_in,
                              void* d_out, int out_size, void* d_ws, size_t ws_size,
                              hipStream_t stream) {
    const float* x  = (const float*)d_in[0];
    const float* Wq = (const float*)d_in[1];
    const float* Wk = (const float*)d_in[2];
    const float* Wv = (const float*)d_in[3];
    const float* Wo = (const float*)d_in[4];
    const float* bo = (const float*)d_in[5];
    float* out = (float*)d_out;

    float* ws     = (float*)d_ws;
    float* r      = ws;                        // B*H*F            = 16384
    float* ycp    = r + BB * HH * FF;          // B*NCHUNK*H*F     = 524288
    float* ml     = ycp + (size_t)BB * NCHUNK * HH * FF; // B*NCHUNK*2*H = 4096
    float* attn_g = ml + BB * NCHUNK * 2 * HH; // B*PROJ           = 4096

    k_qr<<<BB * HH, 256, 0, stream>>>(x, Wq, Wk, r);
    k_fa<<<BB * NCHUNK, 512, 0, stream>>>(x, r, ycp, ml);
    k_comb<<<BB * HH, 256, 0, stream>>>(ycp, ml, Wv, attn_g);
    k_out2<<<BB, 1024, 0, stream>>>(attn_g, Wo, bo, out);
}